// Round 1
// baseline (5239.977 us; speedup 1.0000x reference)
//
#include <hip/hip_runtime.h>
#include <stdint.h>
#include <stddef.h>

typedef unsigned short u16;
typedef unsigned int u32;

typedef __attribute__((ext_vector_type(8))) short bf16x8;   // 8 bf16 = 4 VGPRs (MFMA A/B frag)
typedef __attribute__((ext_vector_type(4))) float f32x4;    // MFMA C/D frag

#define DEV __device__ __forceinline__

DEV u16 f2bf(float f) {
  union { float f; u32 u; } v; v.f = f;
  u32 r = v.u + 0x7FFFu + ((v.u >> 16) & 1u);   // RNE
  return (u16)(r >> 16);
}
DEV float bf2f(u16 h) {
  union { u32 u; float f; } v; v.u = ((u32)h) << 16;
  return v.f;
}
DEV float frcp(float x) { return __builtin_amdgcn_rcpf(x); }
DEV float sigm(float x) { return frcp(1.0f + __expf(-x)); }
DEV float tanh_(float x) { return 2.0f * frcp(1.0f + __expf(-2.0f * x)) - 1.0f; }

// pack 8 consecutive fp32 -> 8 bf16 -> 16B store to LDS
DEV void pack8(const float* __restrict__ src, u16* dst) {
  float4 x = *(const float4*)src;
  float4 y = *(const float4*)(src + 4);
  union { u16 us[8]; uint4 v; } t;
  t.us[0] = f2bf(x.x); t.us[1] = f2bf(x.y); t.us[2] = f2bf(x.z); t.us[3] = f2bf(x.w);
  t.us[4] = f2bf(y.x); t.us[5] = f2bf(y.y); t.us[6] = f2bf(y.z); t.us[7] = f2bf(y.w);
  *(uint4*)dst = t.v;
}

// ---------------------------------------------------------------------------
// Generic 128x128-tile bf16 MFMA GEMM, C = A[M,K] * B[N,K]^T + bias
// A is bf16. B is fp32 (converted in staging) or bf16. C is fp32 or bf16.
// grid = (M/128, ceil(N/128)), block = 256 (4 waves, 2x2, each 64x64).
// ---------------------------------------------------------------------------
__global__ __launch_bounds__(256) void gemm128_bt(
    const u16* __restrict__ A, int lda,
    const void* __restrict__ Bv, int ldb, int b_fp32,
    const float* __restrict__ bias,
    void* __restrict__ Cv, int ldc, int c_bf16,
    int N, int K)
{
  const int mBase = blockIdx.x * 128;
  const int nBase = blockIdx.y * 128;
  __shared__ u16 As[128 * 32];
  __shared__ u16 Bs[128 * 32];
  const int tid = threadIdx.x;
  const int lane = tid & 63;
  const int w = tid >> 6;
  const int wm = w >> 1, wn = w & 1;
  const int fr = (lane & 15);      // frag row (m or n within 16)
  const int fq = (lane >> 4);      // quad -> k offset fq*8

  f32x4 acc[4][4] = {};
  const int nk = K >> 5;
  for (int kt = 0; kt < nk; ++kt) {
    const int k0 = kt << 5;
    // stage A: 128x32 bf16 = 512 16B-chunks; 2 per thread
    {
      int row0 = tid >> 2, k8 = (tid & 3) << 3;
      *(uint4*)&As[row0 * 32 + k8] =
          *(const uint4*)(A + (size_t)(mBase + row0) * lda + k0 + k8);
      int row1 = row0 + 64;
      *(uint4*)&As[row1 * 32 + k8] =
          *(const uint4*)(A + (size_t)(mBase + row1) * lda + k0 + k8);
    }
    // stage B (row n holds B^T row = original B row n, contiguous K)
    {
      int row0 = tid >> 2, k8 = (tid & 3) << 3;
      for (int q = 0; q < 2; ++q) {
        int row = row0 + q * 64;
        int brow = nBase + row; if (brow > N - 1) brow = N - 1;   // N-edge clamp
        if (b_fp32) {
          pack8((const float*)Bv + (size_t)brow * ldb + k0 + k8, &Bs[row * 32 + k8]);
        } else {
          *(uint4*)&Bs[row * 32 + k8] =
              *(const uint4*)((const u16*)Bv + (size_t)brow * ldb + k0 + k8);
        }
      }
    }
    __syncthreads();
    bf16x8 af[4], bfr[4];
#pragma unroll
    for (int i = 0; i < 4; ++i) {
      af[i]  = *(const bf16x8*)&As[(wm * 64 + i * 16 + fr) * 32 + fq * 8];
      bfr[i] = *(const bf16x8*)&Bs[(wn * 64 + i * 16 + fr) * 32 + fq * 8];
    }
#pragma unroll
    for (int mi = 0; mi < 4; ++mi)
#pragma unroll
      for (int ni = 0; ni < 4; ++ni)
        acc[mi][ni] = __builtin_amdgcn_mfma_f32_16x16x32_bf16(af[mi], bfr[ni], acc[mi][ni], 0, 0, 0);
    __syncthreads();
  }
  // epilogue: C row = quad*4+reg, col = lane&15 (m89-verified C/D layout)
#pragma unroll
  for (int mi = 0; mi < 4; ++mi) {
    int row = mBase + wm * 64 + mi * 16 + fq * 4;
#pragma unroll
    for (int ni = 0; ni < 4; ++ni) {
      int col = nBase + wn * 64 + ni * 16 + fr;
      if (col < N) {
        float bv = bias ? bias[col] : 0.0f;
#pragma unroll
        for (int r = 0; r < 4; ++r) {
          float v = acc[mi][ni][r] + bv;
          if (c_bf16) ((u16*)Cv)[(size_t)(row + r) * ldc + col] = f2bf(v);
          else        ((float*)Cv)[(size_t)(row + r) * ldc + col] = v;
        }
      }
    }
  }
}

// ---------------------------------------------------------------------------
// M=64 GEMM: C[64,N] = A[64,K](bf16) * B[N,K]^T(fp32, row-split across B0/B1)
// + bias (split at same row). grid = N/64, block = 256 (4 waves 2x2, 32x32 each).
// Optionally copies Emb_all[:,t,:] -> Abuf cols 0:512 (blocks 0..15).
// ---------------------------------------------------------------------------
__global__ __launch_bounds__(256) void gemm64_bt(
    const u16* __restrict__ A, int lda,
    const float* __restrict__ B0, int ldb0,
    const float* __restrict__ B1, int ldb1, int rowsplit,
    const float* __restrict__ bias0, const float* __restrict__ bias1,
    float* __restrict__ C, int ldc, int K,
    const u16* __restrict__ embsrc, u16* __restrict__ abuf, int t)
{
  if (embsrc && blockIdx.x < 16) {
    int c = blockIdx.x * 256 + threadIdx.x;            // 4096 chunks of 8 bf16
    int bb = c >> 6, col8 = (c & 63) << 3;
    *(uint4*)&abuf[(size_t)bb * 2304 + col8] =
        *(const uint4*)&embsrc[(size_t)(bb * 32 + t) * 512 + col8];
  }
  const int nBase = blockIdx.x * 64;
  __shared__ u16 As[64 * 32];
  __shared__ u16 Bs[64 * 32];
  const int tid = threadIdx.x;
  const int lane = tid & 63;
  const int w = tid >> 6;
  const int wm = w >> 1, wn = w & 1;
  const int fr = (lane & 15), fq = (lane >> 4);

  f32x4 acc[2][2] = {};
  const int nk = K >> 5;
  for (int kt = 0; kt < nk; ++kt) {
    const int k0 = kt << 5;
    int row = tid >> 2, k8 = (tid & 3) << 3;
    *(uint4*)&As[row * 32 + k8] = *(const uint4*)(A + (size_t)row * lda + k0 + k8);
    int brow = nBase + row;
    const float* bp; int ldb;
    if (brow < rowsplit) { bp = B0; ldb = ldb0; }
    else { bp = B1; ldb = ldb1; brow -= rowsplit; }
    pack8(bp + (size_t)brow * ldb + k0 + k8, &Bs[row * 32 + k8]);
    __syncthreads();
    bf16x8 af[2], bfr[2];
#pragma unroll
    for (int i = 0; i < 2; ++i) {
      af[i]  = *(const bf16x8*)&As[(wm * 32 + i * 16 + fr) * 32 + fq * 8];
      bfr[i] = *(const bf16x8*)&Bs[(wn * 32 + i * 16 + fr) * 32 + fq * 8];
    }
#pragma unroll
    for (int mi = 0; mi < 2; ++mi)
#pragma unroll
      for (int ni = 0; ni < 2; ++ni)
        acc[mi][ni] = __builtin_amdgcn_mfma_f32_16x16x32_bf16(af[mi], bfr[ni], acc[mi][ni], 0, 0, 0);
    __syncthreads();
  }
#pragma unroll
  for (int mi = 0; mi < 2; ++mi) {
    int row = wm * 32 + mi * 16 + fq * 4;
#pragma unroll
    for (int ni = 0; ni < 2; ++ni) {
      int col = nBase + wn * 32 + ni * 16 + fr;
      float bv = (col < rowsplit) ? bias0[col] : bias1[col - rowsplit];
#pragma unroll
      for (int r = 0; r < 4; ++r)
        C[(size_t)(row + r) * ldc + col] = acc[mi][ni][r] + bv;
    }
  }
}

// ---------------------------------------------------------------------------
// Fused attention: one block per (b, which). which=0: features (N=196,D=512),
// which=1: articles (N=64,D=768). scores->softmax->alpha(out)->ctx(bf16->Abuf)
// ---------------------------------------------------------------------------
__global__ __launch_bounds__(256) void attend_kernel(
    const u16* __restrict__ u_feat, const u16* __restrict__ u_art,
    const u16* __restrict__ feats_bf, const u16* __restrict__ arts_bf,
    const float* __restrict__ w_ah,
    const float* __restrict__ attAw, const float* __restrict__ attAb,
    const float* __restrict__ paAw, const float* __restrict__ paAb,
    u16* __restrict__ Abuf, float* __restrict__ out_alpha,
    float* __restrict__ out_pa, int t)
{
  const int which = blockIdx.x & 1, b = blockIdx.x >> 1;
  const int Nn = which ? 64 : 196;
  const int Dd = which ? 768 : 512;
  const u16* u  = which ? u_art + (size_t)b * 64 * 512 : u_feat + (size_t)b * 196 * 512;
  const u16* fe = which ? arts_bf + (size_t)b * 64 * 768 : feats_bf + (size_t)b * 196 * 512;
  const float* wv_g = w_ah + (size_t)b * 1024 + which * 512;
  const float* Aw = which ? paAw : attAw;
  const float Ab = which ? paAb[0] : attAb[0];
  float* aout = which ? out_pa + (size_t)(b * 32 + t) * 64
                      : out_alpha + (size_t)(b * 32 + t) * 196;
  u16* ctxDst = Abuf + (size_t)b * 2304 + (which ? 1024 : 512);

  __shared__ float sc[196];
  __shared__ float red2[2];
  const int tid = threadIdx.x;
  const int lane = tid & 63;
  const int w = tid >> 6;

  // hoist per-lane slices of w_ah and A_w into registers (avoids LDS conflicts)
  float wvr[8], awr[8];
#pragma unroll
  for (int j = 0; j < 8; ++j) {
    wvr[j] = wv_g[lane * 8 + j];
    awr[j] = Aw[lane * 8 + j];
  }
  // scores
  for (int n = w; n < Nn; n += 4) {
    union { uint4 v; u16 us[8]; } uv;
    uv.v = *(const uint4*)(u + (size_t)n * 512 + lane * 8);
    float p = 0.0f;
#pragma unroll
    for (int j = 0; j < 8; ++j)
      p += tanh_(bf2f(uv.us[j]) + wvr[j]) * awr[j];
#pragma unroll
    for (int off = 32; off > 0; off >>= 1) p += __shfl_down(p, off);
    if (lane == 0) sc[n] = p + Ab;
  }
  __syncthreads();
  // softmax stats (wave 0)
  if (w == 0) {
    float m = -1e30f;
    for (int n = lane; n < Nn; n += 64) m = fmaxf(m, sc[n]);
#pragma unroll
    for (int off = 32; off > 0; off >>= 1) m = fmaxf(m, __shfl_xor(m, off));
    float s = 0.0f;
    for (int n = lane; n < Nn; n += 64) s += __expf(sc[n] - m);
#pragma unroll
    for (int off = 32; off > 0; off >>= 1) s += __shfl_xor(s, off);
    if (lane == 0) { red2[0] = m; red2[1] = s; }
  }
  __syncthreads();
  const float m = red2[0], inv = frcp(red2[1]);
  for (int n = tid; n < Nn; n += 256) {
    float a = __expf(sc[n] - m) * inv;
    sc[n] = a;
    aout[n] = a;
  }
  __syncthreads();
  // ctx[d] = sum_n alpha[n] * feats[n,d]; each thread owns d = tid + q*256
  float a3[3] = {0.f, 0.f, 0.f};
  const int nd = (Dd + 255) >> 8;
  for (int n = 0; n < Nn; ++n) {
    float a = sc[n];
    const u16* fp = fe + (size_t)n * Dd + tid;
#pragma unroll 3
    for (int q = 0; q < nd; ++q) a3[q] += a * bf2f(fp[q * 256]);
  }
  for (int q = 0; q < nd; ++q) ctxDst[tid + q * 256] = f2bf(a3[q]);
}

// ---------------------------------------------------------------------------
// Gates GEMM + LSTM cell, fused. grid=32 (j = 16-col strip), block=256.
// Wave g computes gate g's [64 x 16] slice over K=2304 ([x|h] @ [Wih|Whh]^T),
// exchange via LDS, then cell epilogue -> c(fp32), h(bf16 -> Abuf & Hall).
// ---------------------------------------------------------------------------
__global__ __launch_bounds__(256) void gates_cell(
    const u16* __restrict__ Abuf,
    const float* __restrict__ Wih, const float* __restrict__ Whh,
    const float* __restrict__ bih, const float* __restrict__ bhh,
    float* __restrict__ cbuf, u16* __restrict__ abuf_h,
    u16* __restrict__ Hall, int t)
{
  __shared__ u16 As[64 * 32];
  __shared__ u16 Bs[64 * 32];           // 4 gates x 16 rows x 32 k
  __shared__ float Gex[4][64 * 16];
  const int tid = threadIdx.x;
  const int lane = tid & 63;
  const int g = tid >> 6;               // wave = gate (i,f,g,o)
  const int j = blockIdx.x;             // column strip
  const int fr = (lane & 15), fq = (lane >> 4);

  f32x4 acc[4] = {};
  for (int kt = 0; kt < 72; ++kt) {
    const int k0 = kt << 5;
    {
      int row = tid >> 2, k8 = (tid & 3) << 3;
      *(uint4*)&As[row * 32 + k8] = *(const uint4*)(Abuf + (size_t)row * 2304 + k0 + k8);
    }
    {
      int r = lane >> 2, k8 = (lane & 3) << 3;
      int brow = g * 512 + j * 16 + r;
      const float* src = (k0 < 1792) ? (Wih + (size_t)brow * 1792 + k0 + k8)
                                     : (Whh + (size_t)brow * 512 + (k0 - 1792) + k8);
      pack8(src, &Bs[(g * 16 + r) * 32 + k8]);
    }
    __syncthreads();
    bf16x8 bfr = *(const bf16x8*)&Bs[(g * 16 + fr) * 32 + fq * 8];
#pragma unroll
    for (int mi = 0; mi < 4; ++mi) {
      bf16x8 af = *(const bf16x8*)&As[(mi * 16 + fr) * 32 + fq * 8];
      acc[mi] = __builtin_amdgcn_mfma_f32_16x16x32_bf16(af, bfr, acc[mi], 0, 0, 0);
    }
    __syncthreads();
  }
  // dump gate slice to LDS: element (m, dl)
#pragma unroll
  for (int mi = 0; mi < 4; ++mi) {
    int mrow = mi * 16 + fq * 4;
#pragma unroll
    for (int r = 0; r < 4; ++r)
      Gex[g][(mrow + r) * 16 + fr] = acc[mi][r];
  }
  __syncthreads();
  // cell: 1024 elements (b, dl), 4 per thread
#pragma unroll
  for (int q = 0; q < 4; ++q) {
    int e = tid + q * 256;
    int b = e >> 4, dl = e & 15;
    int d = j * 16 + dl;
    float iv = Gex[0][e] + bih[d] + bhh[d];
    float fv = Gex[1][e] + bih[512 + d] + bhh[512 + d];
    float gv = Gex[2][e] + bih[1024 + d] + bhh[1024 + d];
    float ov = Gex[3][e] + bih[1536 + d] + bhh[1536 + d];
    float c_old = cbuf[b * 512 + d];
    float cn = sigm(fv) * c_old + sigm(iv) * tanh_(gv);
    float hn = sigm(ov) * tanh_(cn);
    cbuf[b * 512 + d] = cn;
    u16 hb = f2bf(hn);
    abuf_h[(size_t)b * 2304 + 1792 + d] = hb;
    Hall[(size_t)(b * 32 + t) * 512 + d] = hb;
  }
}

// --------------------------- small setup kernels ---------------------------

__global__ void convert_bf16_k(const float* __restrict__ src, u16* __restrict__ dst) {
  size_t i4 = ((size_t)blockIdx.x * 256 + threadIdx.x) * 4;
  float4 v = *(const float4*)(src + i4);
  union { u16 us[4]; uint2 u; } t;
  t.us[0] = f2bf(v.x); t.us[1] = f2bf(v.y); t.us[2] = f2bf(v.z); t.us[3] = f2bf(v.w);
  *(uint2*)(dst + i4) = t.u;
}

__global__ void gather_emb_k(const int* __restrict__ captions, const float* __restrict__ emb,
                             u16* __restrict__ Emb_all) {
  int c = blockIdx.x * 256 + threadIdx.x;   // 262144 chunks of 4
  int r = c >> 7;                            // row = b*32+s
  int c4 = (c & 127) << 2;
  int v = captions[r];
  float4 x = *(const float4*)(emb + (size_t)v * 512 + c4);
  union { u16 us[4]; uint2 u; } t;
  t.us[0] = f2bf(x.x); t.us[1] = f2bf(x.y); t.us[2] = f2bf(x.z); t.us[3] = f2bf(x.w);
  *(uint2*)(Emb_all + (size_t)r * 512 + c4) = t.u;
}

__global__ void meanpool_k(const float* __restrict__ features, const float* __restrict__ articles,
                           u16* __restrict__ inp0_bf) {
  int b = blockIdx.x, tid = threadIdx.x;
  for (int d = tid; d < 1280; d += 256) {
    float s = 0.0f;
    if (d < 512) {
      for (int n = 0; n < 196; ++n) s += features[((size_t)b * 196 + n) * 512 + d];
      s *= (1.0f / 196.0f);
    } else {
      int dd = d - 512;
      for (int n = 0; n < 64; ++n) s += articles[((size_t)b * 64 + n) * 768 + dd];
      s *= (1.0f / 64.0f);
    }
    inp0_bf[b * 1280 + d] = f2bf(s);
  }
}

__global__ void h0prep_k(const float* __restrict__ hbuf, u16* __restrict__ Abuf) {
  int i = blockIdx.x * 256 + threadIdx.x;     // 32768
  Abuf[(size_t)(i >> 9) * 2304 + 1792 + (i & 511)] = f2bf(hbuf[i]);
}

// ---------------------------------------------------------------------------

extern "C" void kernel_launch(void* const* d_in, const int* in_sizes, int n_in,
                              void* d_out, int out_size, void* d_ws, size_t ws_size,
                              hipStream_t stream) {
  const float* features = (const float*)d_in[0];
  const float* articles = (const float*)d_in[1];
  const int*   captions = (const int*)d_in[2];
  const float* emb      = (const float*)d_in[3];
  const float* att_W_w  = (const float*)d_in[4];
  const float* att_W_b  = (const float*)d_in[5];
  const float* att_U_w  = (const float*)d_in[6];
  const float* att_U_b  = (const float*)d_in[7];
  const float* att_A_w  = (const float*)d_in[8];
  const float* att_A_b  = (const float*)d_in[9];
  const float* pa_W_w   = (const float*)d_in[10];
  const float* pa_W_b   = (const float*)d_in[11];
  const float* pa_U_w   = (const float*)d_in[12];
  const float* pa_U_b   = (const float*)d_in[13];
  const float* pa_A_w   = (const float*)d_in[14];
  const float* pa_A_b   = (const float*)d_in[15];
  const float* init_h_w = (const float*)d_in[16];
  const float* init_h_b = (const float*)d_in[17];
  const float* init_c_w = (const float*)d_in[18];
  const float* init_c_b = (const float*)d_in[19];
  const float* lstm_w_ih = (const float*)d_in[20];
  const float* lstm_w_hh = (const float*)d_in[21];
  const float* lstm_b_ih = (const float*)d_in[22];
  const float* lstm_b_hh = (const float*)d_in[23];
  const float* fcn_w    = (const float*)d_in[24];
  const float* fcn_b    = (const float*)d_in[25];

  float* out = (float*)d_out;
  float* out_preds = out;                       // [64,32,30000]
  float* out_alpha = out + 61440000ull;         // [64,32,196]
  float* out_pa    = out + 61841408ull;         // [64,32,64]

  uintptr_t p = (uintptr_t)d_ws;
  auto take = [&](size_t bytes) -> uintptr_t {
    uintptr_t r = p; p += (bytes + 255) & ~(size_t)255; return r;
  };
  u16* features_bf = (u16*)take(6422528ull * 2);   // [64*196, 512]
  u16* articles_bf = (u16*)take(3145728ull * 2);   // [64*64, 768]
  u16* u_feat      = (u16*)take(6422528ull * 2);   // [64*196, 512] bf16
  u16* u_art       = (u16*)take(2097152ull * 2);   // [64*64, 512] bf16
  u16* fcn_bf      = (u16*)take(15360000ull * 2);  // [30000, 512]
  u16* Emb_all     = (u16*)take(2048ull * 512 * 2);
  u16* inp0_bf     = (u16*)take(64ull * 1280 * 2);
  float* hbuf      = (float*)take(64ull * 512 * 4);
  float* cbuf      = (float*)take(64ull * 512 * 4);
  u16* Abuf        = (u16*)take(64ull * 2304 * 2); // [emb|ctx|pctx|h] per b
  float* w_ah      = (float*)take(64ull * 1024 * 4);
  u16* Hall        = (u16*)take(2048ull * 512 * 2);
  (void)ws_size; (void)in_sizes; (void)n_in; (void)out_size;

  // ---- one-time setup ----
  convert_bf16_k<<<6272, 256, 0, stream>>>(features, features_bf);
  convert_bf16_k<<<3072, 256, 0, stream>>>(articles, articles_bf);
  convert_bf16_k<<<15000, 256, 0, stream>>>(fcn_w, fcn_bf);
  gather_emb_k<<<1024, 256, 0, stream>>>(captions, emb, Emb_all);
  meanpool_k<<<64, 256, 0, stream>>>(features, articles, inp0_bf);
  // u_feat = features @ att_U_w^T + b (bf16 out)
  gemm128_bt<<<dim3(98, 4), 256, 0, stream>>>(features_bf, 512, att_U_w, 512, 1,
                                              att_U_b, u_feat, 512, 1, 512, 512);
  // u_art = articles @ pa_U_w^T + b (bf16 out)
  gemm128_bt<<<dim3(32, 4), 256, 0, stream>>>(articles_bf, 768, pa_U_w, 768, 1,
                                              pa_U_b, u_art, 512, 1, 512, 768);
  // h0, c0
  gemm64_bt<<<8, 256, 0, stream>>>(inp0_bf, 1280, init_h_w, 1280, init_h_w, 1280,
                                   1 << 30, init_h_b, init_h_b, hbuf, 512, 1280,
                                   nullptr, nullptr, 0);
  gemm64_bt<<<8, 256, 0, stream>>>(inp0_bf, 1280, init_c_w, 1280, init_c_w, 1280,
                                   1 << 30, init_c_b, init_c_b, cbuf, 512, 1280,
                                   nullptr, nullptr, 0);
  h0prep_k<<<128, 256, 0, stream>>>(hbuf, Abuf);

  // ---- recurrence ----
  for (int t = 0; t < 32; ++t) {
    // w_ah = h @ [attW; paW]^T (+ emb_t copy into Abuf cols 0:512)
    gemm64_bt<<<16, 256, 0, stream>>>(Abuf + 1792, 2304, att_W_w, 512, pa_W_w, 512,
                                      512, att_W_b, pa_W_b, w_ah, 1024, 512,
                                      Emb_all, Abuf, t);
    attend_kernel<<<128, 256, 0, stream>>>(u_feat, u_art, features_bf, articles_bf,
                                           w_ah, att_A_w, att_A_b, pa_A_w, pa_A_b,
                                           Abuf, out_alpha, out_pa, t);
    gates_cell<<<32, 256, 0, stream>>>(Abuf, lstm_w_ih, lstm_w_hh, lstm_b_ih,
                                       lstm_b_hh, cbuf, Abuf, Hall, t);
  }

  // ---- preds = Hall @ fcn_w^T + fcn_b ----
  gemm128_bt<<<dim3(16, 235), 256, 0, stream>>>(Hall, 512, fcn_bf, 512, 0,
                                                fcn_b, out_preds, 30000, 0,
                                                30000, 512);
}

// Round 2
// 2876.602 us; speedup vs baseline: 1.8216x; 1.8216x over previous
//
#include <hip/hip_runtime.h>
#include <stdint.h>
#include <stddef.h>

typedef unsigned short u16;
typedef unsigned int u32;

typedef __attribute__((ext_vector_type(8))) short bf16x8;   // 8 bf16 (MFMA A/B frag)
typedef __attribute__((ext_vector_type(4))) float f32x4;    // MFMA C/D frag

#define DEV __device__ __forceinline__

DEV u16 f2bf(float f) {
  union { float f; u32 u; } v; v.f = f;
  u32 r = v.u + 0x7FFFu + ((v.u >> 16) & 1u);   // RNE
  return (u16)(r >> 16);
}
DEV float bf2f(u16 h) {
  union { u32 u; float f; } v; v.u = ((u32)h) << 16;
  return v.f;
}
DEV float frcp(float x) { return __builtin_amdgcn_rcpf(x); }
DEV float sigm(float x) { return frcp(1.0f + __expf(-x)); }
DEV float tanh_(float x) { return 2.0f * frcp(1.0f + __expf(-2.0f * x)) - 1.0f; }

DEV void pack8(const float* __restrict__ src, u16* dst) {
  float4 x = *(const float4*)src;
  float4 y = *(const float4*)(src + 4);
  union { u16 us[8]; uint4 v; } t;
  t.us[0] = f2bf(x.x); t.us[1] = f2bf(x.y); t.us[2] = f2bf(x.z); t.us[3] = f2bf(x.w);
  t.us[4] = f2bf(y.x); t.us[5] = f2bf(y.y); t.us[6] = f2bf(y.z); t.us[7] = f2bf(y.w);
  *(uint4*)dst = t.v;
}

// ---------------------------------------------------------------------------
// 128x128-tile bf16 MFMA GEMM, C = A[M,K] * B[N,K]^T + bias.
// LDS rows padded to 40 elems (80 B = 20 banks -> 2-way, free).
// swz=1: XCD-locality swizzle (requires mtiles==16, grid (16, 8*ceil(nt/8))):
// each XCD owns one N-strip per 128-block group -> B fetched once from HBM.
// ---------------------------------------------------------------------------
__global__ __launch_bounds__(256) void gemm128_bt(
    const u16* __restrict__ A, int lda,
    const void* __restrict__ Bv, int ldb, int b_fp32,
    const float* __restrict__ bias,
    void* __restrict__ Cv, int ldc, int c_bf16,
    int N, int K, int swz)
{
  int m_tile, n_tile;
  if (swz) {
    int lin = blockIdx.y * gridDim.x + blockIdx.x;
    int idx = lin & 127;
    n_tile = (lin >> 7) * 8 + (idx & 7);
    m_tile = idx >> 3;
    if (n_tile >= ((N + 127) >> 7)) return;
  } else { m_tile = blockIdx.x; n_tile = blockIdx.y; }
  const int mBase = m_tile * 128;
  const int nBase = n_tile * 128;
  __shared__ u16 As[128 * 40];
  __shared__ u16 Bs[128 * 40];
  const int tid = threadIdx.x;
  const int lane = tid & 63;
  const int w = tid >> 6;
  const int wm = w >> 1, wn = w & 1;
  const int fr = (lane & 15);
  const int fq = (lane >> 4);

  f32x4 acc[4][4] = {};
  const int nk = K >> 5;
  for (int kt = 0; kt < nk; ++kt) {
    const int k0 = kt << 5;
    {
      int row0 = tid >> 2, k8 = (tid & 3) << 3;
      *(uint4*)&As[row0 * 40 + k8] =
          *(const uint4*)(A + (size_t)(mBase + row0) * lda + k0 + k8);
      int row1 = row0 + 64;
      *(uint4*)&As[row1 * 40 + k8] =
          *(const uint4*)(A + (size_t)(mBase + row1) * lda + k0 + k8);
    }
    {
      int row0 = tid >> 2, k8 = (tid & 3) << 3;
      for (int q = 0; q < 2; ++q) {
        int row = row0 + q * 64;
        int brow = nBase + row; if (brow > N - 1) brow = N - 1;
        if (b_fp32) {
          pack8((const float*)Bv + (size_t)brow * ldb + k0 + k8, &Bs[row * 40 + k8]);
        } else {
          *(uint4*)&Bs[row * 40 + k8] =
              *(const uint4*)((const u16*)Bv + (size_t)brow * ldb + k0 + k8);
        }
      }
    }
    __syncthreads();
    bf16x8 af[4], bfr[4];
#pragma unroll
    for (int i = 0; i < 4; ++i) {
      af[i]  = *(const bf16x8*)&As[(wm * 64 + i * 16 + fr) * 40 + fq * 8];
      bfr[i] = *(const bf16x8*)&Bs[(wn * 64 + i * 16 + fr) * 40 + fq * 8];
    }
#pragma unroll
    for (int mi = 0; mi < 4; ++mi)
#pragma unroll
      for (int ni = 0; ni < 4; ++ni)
        acc[mi][ni] = __builtin_amdgcn_mfma_f32_16x16x32_bf16(af[mi], bfr[ni], acc[mi][ni], 0, 0, 0);
    __syncthreads();
  }
#pragma unroll
  for (int mi = 0; mi < 4; ++mi) {
    int row = mBase + wm * 64 + mi * 16 + fq * 4;
#pragma unroll
    for (int ni = 0; ni < 4; ++ni) {
      int col = nBase + wn * 64 + ni * 16 + fr;
      if (col < N) {
        float bv = bias ? bias[col] : 0.0f;
#pragma unroll
        for (int r = 0; r < 4; ++r) {
          float v = acc[mi][ni][r] + bv;
          if (c_bf16) ((u16*)Cv)[(size_t)(row + r) * ldc + col] = f2bf(v);
          else        ((float*)Cv)[(size_t)(row + r) * ldc + col] = v;
        }
      }
    }
  }
}

// ---------------------------------------------------------------------------
// Setup-only M=64 GEMM (h0/c0): C[64,N] = A[64,K](bf16) @ B[N,K]^T(fp32) + bias
// ---------------------------------------------------------------------------
__global__ __launch_bounds__(256) void gemm64_bt(
    const u16* __restrict__ A, int lda,
    const float* __restrict__ B, int ldb,
    const float* __restrict__ bias,
    float* __restrict__ C, int ldc, int K)
{
  const int nBase = blockIdx.x * 64;
  __shared__ u16 As[64 * 40];
  __shared__ u16 Bs[64 * 40];
  const int tid = threadIdx.x;
  const int lane = tid & 63;
  const int w = tid >> 6;
  const int wm = w >> 1, wn = w & 1;
  const int fr = (lane & 15), fq = (lane >> 4);

  f32x4 acc[2][2] = {};
  const int nk = K >> 5;
  for (int kt = 0; kt < nk; ++kt) {
    const int k0 = kt << 5;
    int row = tid >> 2, k8 = (tid & 3) << 3;
    *(uint4*)&As[row * 40 + k8] = *(const uint4*)(A + (size_t)row * lda + k0 + k8);
    pack8(B + (size_t)(nBase + row) * ldb + k0 + k8, &Bs[row * 40 + k8]);
    __syncthreads();
    bf16x8 af[2], bfr[2];
#pragma unroll
    for (int i = 0; i < 2; ++i) {
      af[i]  = *(const bf16x8*)&As[(wm * 32 + i * 16 + fr) * 40 + fq * 8];
      bfr[i] = *(const bf16x8*)&Bs[(wn * 32 + i * 16 + fr) * 40 + fq * 8];
    }
#pragma unroll
    for (int mi = 0; mi < 2; ++mi)
#pragma unroll
      for (int ni = 0; ni < 2; ++ni)
        acc[mi][ni] = __builtin_amdgcn_mfma_f32_16x16x32_bf16(af[mi], bfr[ni], acc[mi][ni], 0, 0, 0);
    __syncthreads();
  }
#pragma unroll
  for (int mi = 0; mi < 2; ++mi) {
    int row = wm * 32 + mi * 16 + fq * 4;
#pragma unroll
    for (int ni = 0; ni < 2; ++ni) {
      int col = nBase + wn * 32 + ni * 16 + fr;
#pragma unroll
      for (int r = 0; r < 4; ++r)
        C[(size_t)(row + r) * ldc + col] = acc[mi][ni][r] + bias[col];
    }
  }
}

// ---------------------------------------------------------------------------
// Per-step w_ah GEMM: w_ah[64,1024] = h[64,512] @ Wcat[1024,512]^T + bias.
// h = Abuf col 1280, row stride 1792. grid=16, block=256 (wave w = 16 cols).
// BK=64 -> 8 iterations.
// ---------------------------------------------------------------------------
__global__ __launch_bounds__(256) void step_wah(
    const u16* __restrict__ Abuf,
    const u16* __restrict__ Watt,
    const float* __restrict__ attWb, const float* __restrict__ paWb,
    float* __restrict__ w_ah)
{
  __shared__ u16 As[64 * 72];
  __shared__ u16 Bs[64 * 72];
  const int tid = threadIdx.x, lane = tid & 63, w = tid >> 6;
  const int fr = lane & 15, fq = lane >> 4;
  const int nBase = blockIdx.x * 64;
  f32x4 acc[4] = {};
  for (int kt = 0; kt < 8; ++kt) {
    const int k0 = kt * 64;
    int row = tid >> 2, kc = (tid & 3) << 3;  // chunks kc, kc+32
    const u16* asrc = Abuf + (size_t)row * 1792 + 1280 + k0 + kc;
    *(uint4*)&As[row * 72 + kc]      = *(const uint4*)asrc;
    *(uint4*)&As[row * 72 + kc + 32] = *(const uint4*)(asrc + 32);
    const u16* bsrc = Watt + (size_t)(nBase + row) * 512 + k0 + kc;
    *(uint4*)&Bs[row * 72 + kc]      = *(const uint4*)bsrc;
    *(uint4*)&Bs[row * 72 + kc + 32] = *(const uint4*)(bsrc + 32);
    __syncthreads();
#pragma unroll
    for (int ks = 0; ks < 2; ++ks) {
      bf16x8 bf = *(const bf16x8*)&Bs[(w * 16 + fr) * 72 + ks * 32 + fq * 8];
#pragma unroll
      for (int mi = 0; mi < 4; ++mi) {
        bf16x8 af = *(const bf16x8*)&As[(mi * 16 + fr) * 72 + ks * 32 + fq * 8];
        acc[mi] = __builtin_amdgcn_mfma_f32_16x16x32_bf16(af, bf, acc[mi], 0, 0, 0);
      }
    }
    __syncthreads();
  }
  const int col = nBase + w * 16 + fr;
  const float bv = (col < 512) ? attWb[col] : paWb[col - 512];
#pragma unroll
  for (int mi = 0; mi < 4; ++mi) {
    int rowb = mi * 16 + fq * 4;
#pragma unroll
    for (int r = 0; r < 4; ++r)
      w_ah[(size_t)(rowb + r) * 1024 + col] = acc[mi][r] + bv;
  }
}

// ---------------------------------------------------------------------------
// Fused dual attention. Block = (b, which). scores -> softmax -> alpha(out)
// -> ctx (vectorized 16B loads, 4-wave n-split, LDS reduce) -> Abuf (bf16).
// ---------------------------------------------------------------------------
__global__ __launch_bounds__(256) void attend_kernel(
    const u16* __restrict__ u_feat, const u16* __restrict__ u_art,
    const u16* __restrict__ feats_bf, const u16* __restrict__ arts_bf,
    const float* __restrict__ w_ah,
    const float* __restrict__ attAw, const float* __restrict__ attAb,
    const float* __restrict__ paAw, const float* __restrict__ paAb,
    u16* __restrict__ Abuf, float* __restrict__ out_alpha,
    float* __restrict__ out_pa, int t)
{
  const int which = blockIdx.x & 1, b = blockIdx.x >> 1;
  const int Nn = which ? 64 : 196;
  const int Dd = which ? 768 : 512;
  const u16* u  = which ? u_art + (size_t)b * 64 * 512 : u_feat + (size_t)b * 196 * 512;
  const u16* fe = which ? arts_bf + (size_t)b * 64 * 768 : feats_bf + (size_t)b * 196 * 512;
  const float* wv_g = w_ah + (size_t)b * 1024 + which * 512;
  const float* Aw = which ? paAw : attAw;
  const float Ab = which ? paAb[0] : attAb[0];
  float* aout = which ? out_pa + (size_t)(b * 32 + t) * 64
                      : out_alpha + (size_t)(b * 32 + t) * 196;
  u16* ctxDst = Abuf + (size_t)b * 1792 + (which ? 512 : 0);

  __shared__ float sc[196];
  __shared__ float red2[2];
  __shared__ float ctxred[4][768];
  const int tid = threadIdx.x;
  const int lane = tid & 63;
  const int w = tid >> 6;

  float wvr[8], awr[8];
#pragma unroll
  for (int j = 0; j < 8; ++j) {
    wvr[j] = wv_g[lane * 8 + j];
    awr[j] = Aw[lane * 8 + j];
  }
  // scores
  for (int n = w; n < Nn; n += 4) {
    union { uint4 v; u16 us[8]; } uv;
    uv.v = *(const uint4*)(u + (size_t)n * 512 + lane * 8);
    float p = 0.0f;
#pragma unroll
    for (int j = 0; j < 8; ++j)
      p += tanh_(bf2f(uv.us[j]) + wvr[j]) * awr[j];
#pragma unroll
    for (int off = 32; off > 0; off >>= 1) p += __shfl_down(p, off);
    if (lane == 0) sc[n] = p + Ab;
  }
  __syncthreads();
  // softmax stats
  if (w == 0) {
    float m = -1e30f;
    for (int n = lane; n < Nn; n += 64) m = fmaxf(m, sc[n]);
#pragma unroll
    for (int off = 32; off > 0; off >>= 1) m = fmaxf(m, __shfl_xor(m, off));
    float s = 0.0f;
    for (int n = lane; n < Nn; n += 64) s += __expf(sc[n] - m);
#pragma unroll
    for (int off = 32; off > 0; off >>= 1) s += __shfl_xor(s, off);
    if (lane == 0) { red2[0] = m; red2[1] = s; }
  }
  __syncthreads();
  const float m = red2[0], inv = frcp(red2[1]);
  for (int n = tid; n < Nn; n += 256) {
    float a = __expf(sc[n] - m) * inv;
    sc[n] = a;
    aout[n] = a;
  }
  __syncthreads();
  // ctx: lane owns 8-elem chunk(s); wave w handles n = w, w+4, ...
  float a0[8] = {0,0,0,0,0,0,0,0}, a1[8] = {0,0,0,0,0,0,0,0};
  const bool two = (Dd == 768) && (lane < 32);
  for (int n = w; n < Nn; n += 4) {
    const float a = sc[n];
    union { uint4 v; u16 us[8]; } v0;
    v0.v = *(const uint4*)(fe + (size_t)n * Dd + lane * 8);
#pragma unroll
    for (int j = 0; j < 8; ++j) a0[j] += a * bf2f(v0.us[j]);
    if (two) {
      union { uint4 v; u16 us[8]; } v1;
      v1.v = *(const uint4*)(fe + (size_t)n * Dd + 512 + lane * 8);
#pragma unroll
      for (int j = 0; j < 8; ++j) a1[j] += a * bf2f(v1.us[j]);
    }
  }
  {
    float4* dst = (float4*)&ctxred[w][lane * 8];
    dst[0] = make_float4(a0[0], a0[1], a0[2], a0[3]);
    dst[1] = make_float4(a0[4], a0[5], a0[6], a0[7]);
    if (two) {
      float4* d2 = (float4*)&ctxred[w][512 + lane * 8];
      d2[0] = make_float4(a1[0], a1[1], a1[2], a1[3]);
      d2[1] = make_float4(a1[4], a1[5], a1[6], a1[7]);
    }
  }
  __syncthreads();
  for (int d = tid; d < Dd; d += 256)
    ctxDst[d] = f2bf(ctxred[0][d] + ctxred[1][d] + ctxred[2][d] + ctxred[3][d]);
}

// ---------------------------------------------------------------------------
// Gates GEMM + LSTM cell. grid=(32 j-strips, 4 batch-groups), block=256.
// Wave g = gate g: 16x16 output tile over K=1792 (BK=128, 14 iters, 4 MFMA).
// Epilogue adds precomputed Gemb (emb@Wih_emb^T + biases) and runs the cell.
// ---------------------------------------------------------------------------
__global__ __launch_bounds__(256) void gates_cell(
    const u16* __restrict__ Abuf,       // [64,1792] = [ctx|pctx|h]
    const u16* __restrict__ Wg,         // [2048,1792] bf16 = [Wih(ctx,pctx)|Whh]
    const float* __restrict__ Gemb,     // [2048,2048] fp32, row b*32+t (biases folded)
    float* __restrict__ cbuf,
    u16* __restrict__ abuf_h,           // Abuf + 1280
    u16* __restrict__ Hall, int t)
{
  __shared__ u16 As[16 * 136];
  __shared__ u16 Bs[64 * 136];
  __shared__ float Gex[4][256];
  const int tid = threadIdx.x, lane = tid & 63, g = tid >> 6;
  const int fr = lane & 15, fq = lane >> 4;
  const int j = blockIdx.x;       // d-strip (16 cols)
  const int mg = blockIdx.y;      // batch group (16 rows)
  f32x4 acc = {};
  for (int kt = 0; kt < 14; ++kt) {
    const int k0 = kt * 128;
    {
      int r = tid >> 4, kc = (tid & 15) << 3;
      *(uint4*)&As[r * 136 + kc] =
          *(const uint4*)(Abuf + (size_t)(mg * 16 + r) * 1792 + k0 + kc);
    }
#pragma unroll
    for (int q = 0; q < 4; ++q) {
      int idx = tid + q * 256;
      int r6 = idx >> 4, kc = (idx & 15) << 3;
      int gg = r6 >> 4, rr = r6 & 15;
      *(uint4*)&Bs[r6 * 136 + kc] =
          *(const uint4*)(Wg + (size_t)(gg * 512 + j * 16 + rr) * 1792 + k0 + kc);
    }
    __syncthreads();
#pragma unroll
    for (int ks = 0; ks < 4; ++ks) {
      bf16x8 af = *(const bf16x8*)&As[fr * 136 + ks * 32 + fq * 8];
      bf16x8 bf = *(const bf16x8*)&Bs[(g * 16 + fr) * 136 + ks * 32 + fq * 8];
      acc = __builtin_amdgcn_mfma_f32_16x16x32_bf16(af, bf, acc, 0, 0, 0);
    }
    __syncthreads();
  }
#pragma unroll
  for (int r = 0; r < 4; ++r)
    Gex[g][(fq * 4 + r) * 16 + fr] = acc[r];
  __syncthreads();
  {
    const int bl = tid >> 4, dl = tid & 15;
    const int b = mg * 16 + bl;
    const int d = j * 16 + dl;
    const float* ge = Gemb + (size_t)(b * 32 + t) * 2048;
    float iv = Gex[0][tid] + ge[d];
    float fv = Gex[1][tid] + ge[512 + d];
    float gv = Gex[2][tid] + ge[1024 + d];
    float ov = Gex[3][tid] + ge[1536 + d];
    float c_old = cbuf[b * 512 + d];
    float cn = sigm(fv) * c_old + sigm(iv) * tanh_(gv);
    float hn = sigm(ov) * tanh_(cn);
    cbuf[b * 512 + d] = cn;
    u16 hb = f2bf(hn);
    abuf_h[(size_t)b * 1792 + d] = hb;
    Hall[(size_t)(b * 32 + t) * 512 + d] = hb;
  }
}

// --------------------------- small setup kernels ---------------------------

__global__ void convert_bf16_k(const float* __restrict__ src, u16* __restrict__ dst) {
  size_t i4 = ((size_t)blockIdx.x * 256 + threadIdx.x) * 4;
  float4 v = *(const float4*)(src + i4);
  union { u16 us[4]; uint2 u; } t;
  t.us[0] = f2bf(v.x); t.us[1] = f2bf(v.y); t.us[2] = f2bf(v.z); t.us[3] = f2bf(v.w);
  *(uint2*)(dst + i4) = t.u;
}

// W_gates[2048,1792] bf16 = [Wih cols 512:1792 | Whh cols 0:512]
__global__ void wgates_k(const float* __restrict__ Wih, const float* __restrict__ Whh,
                         u16* __restrict__ dst) {
  int c = blockIdx.x * 256 + threadIdx.x;     // 458752 chunk-8s
  int r = c / 224;
  int k8 = (c - r * 224) * 8;
  const float* src = (k8 < 1280) ? (Wih + (size_t)r * 1792 + 512 + k8)
                                 : (Whh + (size_t)r * 512 + (k8 - 1280));
  pack8(src, dst + (size_t)r * 1792 + k8);
}

__global__ void biassum_k(const float* __restrict__ a, const float* __restrict__ b,
                          float* __restrict__ dst) {
  int i = blockIdx.x * 256 + threadIdx.x;
  dst[i] = a[i] + b[i];
}

__global__ void gather_emb_k(const int* __restrict__ captions, const float* __restrict__ emb,
                             u16* __restrict__ Emb_all) {
  int c = blockIdx.x * 256 + threadIdx.x;
  int r = c >> 7;
  int c4 = (c & 127) << 2;
  int v = captions[r];
  float4 x = *(const float4*)(emb + (size_t)v * 512 + c4);
  union { u16 us[4]; uint2 u; } t;
  t.us[0] = f2bf(x.x); t.us[1] = f2bf(x.y); t.us[2] = f2bf(x.z); t.us[3] = f2bf(x.w);
  *(uint2*)(Emb_all + (size_t)r * 512 + c4) = t.u;
}

__global__ void meanpool_k(const float* __restrict__ features, const float* __restrict__ articles,
                           u16* __restrict__ inp0_bf) {
  int b = blockIdx.x, tid = threadIdx.x;
  for (int d = tid; d < 1280; d += 256) {
    float s = 0.0f;
    if (d < 512) {
      for (int n = 0; n < 196; ++n) s += features[((size_t)b * 196 + n) * 512 + d];
      s *= (1.0f / 196.0f);
    } else {
      int dd = d - 512;
      for (int n = 0; n < 64; ++n) s += articles[((size_t)b * 64 + n) * 768 + dd];
      s *= (1.0f / 64.0f);
    }
    inp0_bf[b * 1280 + d] = f2bf(s);
  }
}

__global__ void h0prep_k(const float* __restrict__ hbuf, u16* __restrict__ Abuf) {
  int i = blockIdx.x * 256 + threadIdx.x;     // 32768
  Abuf[(size_t)(i >> 9) * 1792 + 1280 + (i & 511)] = f2bf(hbuf[i]);
}

// ---------------------------------------------------------------------------

extern "C" void kernel_launch(void* const* d_in, const int* in_sizes, int n_in,
                              void* d_out, int out_size, void* d_ws, size_t ws_size,
                              hipStream_t stream) {
  const float* features = (const float*)d_in[0];
  const float* articles = (const float*)d_in[1];
  const int*   captions = (const int*)d_in[2];
  const float* emb      = (const float*)d_in[3];
  const float* att_W_w  = (const float*)d_in[4];
  const float* att_W_b  = (const float*)d_in[5];
  const float* att_U_w  = (const float*)d_in[6];
  const float* att_U_b  = (const float*)d_in[7];
  const float* att_A_w  = (const float*)d_in[8];
  const float* att_A_b  = (const float*)d_in[9];
  const float* pa_W_w   = (const float*)d_in[10];
  const float* pa_W_b   = (const float*)d_in[11];
  const float* pa_U_w   = (const float*)d_in[12];
  const float* pa_U_b   = (const float*)d_in[13];
  const float* pa_A_w   = (const float*)d_in[14];
  const float* pa_A_b   = (const float*)d_in[15];
  const float* init_h_w = (const float*)d_in[16];
  const float* init_h_b = (const float*)d_in[17];
  const float* init_c_w = (const float*)d_in[18];
  const float* init_c_b = (const float*)d_in[19];
  const float* lstm_w_ih = (const float*)d_in[20];
  const float* lstm_w_hh = (const float*)d_in[21];
  const float* lstm_b_ih = (const float*)d_in[22];
  const float* lstm_b_hh = (const float*)d_in[23];
  const float* fcn_w    = (const float*)d_in[24];
  const float* fcn_b    = (const float*)d_in[25];

  float* out = (float*)d_out;
  float* out_preds = out;                       // [64,32,30000]
  float* out_alpha = out + 61440000ull;         // [64,32,196]
  float* out_pa    = out + 61841408ull;         // [64,32,64]

  uintptr_t p = (uintptr_t)d_ws;
  auto take = [&](size_t bytes) -> uintptr_t {
    uintptr_t r = p; p += (bytes + 255) & ~(size_t)255; return r;
  };
  u16* features_bf = (u16*)take(6422528ull * 2);   // [64*196,512]; fcn_bf alias after loop
  u16* articles_bf = (u16*)take(3145728ull * 2);   // [64*64,768]
  u16* u_feat      = (u16*)take(6422528ull * 2);   // [64*196,512]
  u16* u_art       = (u16*)take(2097152ull * 2);   // [64*64,512]
  u16* Emb_all     = (u16*)take(2048ull * 512 * 2);
  u16* inp0_bf     = (u16*)take(64ull * 1280 * 2);
  float* hbuf      = (float*)take(64ull * 512 * 4);
  float* cbuf      = (float*)take(64ull * 512 * 4);
  u16* Abuf        = (u16*)take(64ull * 1792 * 2); // [ctx|pctx|h] per b
  float* w_ah      = (float*)take(64ull * 1024 * 4);
  u16* Hall        = (u16*)take(2048ull * 512 * 2);
  u16* Watt        = (u16*)take(1024ull * 512 * 2);
  u16* Wg          = (u16*)take(2048ull * 1792 * 2);
  float* Gemb      = (float*)take(2048ull * 2048 * 4);
  float* bsum      = (float*)take(2048ull * 4);
  u16* fcn_bf      = features_bf;                  // aliased (dead after loop)
  (void)ws_size; (void)in_sizes; (void)n_in; (void)out_size;

  // ---- one-time setup ----
  convert_bf16_k<<<6272, 256, 0, stream>>>(features, features_bf);
  convert_bf16_k<<<3072, 256, 0, stream>>>(articles, articles_bf);
  convert_bf16_k<<<256, 256, 0, stream>>>(att_W_w, Watt);
  convert_bf16_k<<<256, 256, 0, stream>>>(pa_W_w, Watt + 262144);
  wgates_k<<<1792, 256, 0, stream>>>(lstm_w_ih, lstm_w_hh, Wg);
  biassum_k<<<8, 256, 0, stream>>>(lstm_b_ih, lstm_b_hh, bsum);
  gather_emb_k<<<1024, 256, 0, stream>>>(captions, emb, Emb_all);
  meanpool_k<<<64, 256, 0, stream>>>(features, articles, inp0_bf);
  gemm128_bt<<<dim3(98, 4), 256, 0, stream>>>(features_bf, 512, att_U_w, 512, 1,
                                              att_U_b, u_feat, 512, 1, 512, 512, 0);
  gemm128_bt<<<dim3(32, 4), 256, 0, stream>>>(articles_bf, 768, pa_U_w, 768, 1,
                                              pa_U_b, u_art, 512, 1, 512, 768, 0);
  // Gemb[2048,2048] = Emb_all @ Wih[:, :512]^T + (bih + bhh)
  gemm128_bt<<<dim3(16, 16), 256, 0, stream>>>(Emb_all, 512, lstm_w_ih, 1792, 1,
                                               bsum, Gemb, 2048, 0, 2048, 512, 0);
  gemm64_bt<<<8, 256, 0, stream>>>(inp0_bf, 1280, init_h_w, 1280, init_h_b, hbuf, 512, 1280);
  gemm64_bt<<<8, 256, 0, stream>>>(inp0_bf, 1280, init_c_w, 1280, init_c_b, cbuf, 512, 1280);
  h0prep_k<<<128, 256, 0, stream>>>(hbuf, Abuf);

  // ---- recurrence ----
  for (int t = 0; t < 32; ++t) {
    step_wah<<<16, 256, 0, stream>>>(Abuf, Watt, att_W_b, pa_W_b, w_ah);
    attend_kernel<<<128, 256, 0, stream>>>(u_feat, u_art, features_bf, articles_bf,
                                           w_ah, att_A_w, att_A_b, pa_A_w, pa_A_b,
                                           Abuf, out_alpha, out_pa, t);
    gates_cell<<<dim3(32, 4), 256, 0, stream>>>(Abuf, Wg, Gemb, cbuf,
                                                Abuf + 1280, Hall, t);
  }

  // ---- preds = Hall @ fcn_w^T + fcn_b (fcn_bf aliases dead staging region) ----
  convert_bf16_k<<<15000, 256, 0, stream>>>(fcn_w, fcn_bf);
  gemm128_bt<<<dim3(16, 240), 256, 0, stream>>>(Hall, 512, fcn_bf, 512, 0,
                                                fcn_b, out_preds, 30000, 0,
                                                30000, 512, 1);
}